// Round 2
// baseline (812.281 us; speedup 1.0000x reference)
//
#include <hip/hip_runtime.h>
#include <hip/hip_bf16.h>
#include <stdint.h>

#define AS1 __attribute__((address_space(1)))
#define AS3 __attribute__((address_space(3)))

typedef __attribute__((ext_vector_type(8))) __bf16 bf16x8;
typedef __attribute__((ext_vector_type(4))) float f32x4;
typedef unsigned short u16;
typedef __attribute__((ext_vector_type(8))) unsigned short u16x8;

// ---- problem sizes (fixed for this module) ----
#define B_    8
#define S_    512
#define NH_   12
#define HD_   768
#define NHD_  (NH_*HD_)     // 9216
#define D3_   (3*NHD_)      // 27648
#define QK_SCALE 0.03608439182435161f   // 1/sqrt(768)

__device__ __forceinline__ u16 f2bf(float x) {
  union { float f; unsigned u; } a; a.f = x;
  unsigned r = a.u + 0x7fffu + ((a.u >> 16) & 1u);   // RNE
  return (u16)(r >> 16);
}
__device__ __forceinline__ float bf2f(u16 x) {
  union { unsigned u; float f; } a; a.u = ((unsigned)x) << 16; return a.f;
}

__device__ __forceinline__ void gload16(const void* g, void* l) {
  // async global->LDS, 16B per lane; LDS dest = wave-uniform base + lane*16
  __builtin_amdgcn_global_load_lds((const AS1 void*)g, (AS3 void*)l, 16, 0, 0);
}

struct GP {
  const u16* A;   // M x K row-major, lda
  const u16* B;   // N x K row-major, ldb  (C = A * B^T)
  int K, lda, ldb;
  long sA, sB;    // per-blockIdx.z element strides
  void* o0; void* o1; void* o2;
  const float* bias;
};

// MODE 0: QKV proj -> scatter Q,K (zloc,s,h) bf16 and Vt (zloc,h,s) bf16, +bias
// MODE 1: scores   -> S bf16 (zloc,row,col), * QK_SCALE
// MODE 2: AV       -> H bf16 at (bloc*512+row)*9216 + n*768 + col
// MODE 3: out proj -> fp32 (row,col) + bias  (o0 pre-offset to chunk rows)
template<int MODE>
__global__ __launch_bounds__(256)
void gemm_bt(GP p) {
  __shared__ __align__(16) char smem[32768];   // A tile 16KB + B tile 16KB
  const int tid  = threadIdx.x;
  const int wave = tid >> 6, lane = tid & 63;
  const int wr = wave >> 1, wc = wave & 1;     // 2x2 waves, 64x64 each
  const int bm0 = blockIdx.y * 128;
  const int bn0 = blockIdx.x * 128;
  const int z   = blockIdx.z;

  const u16* A  = p.A + (long)z * p.sA;
  const u16* Bm = p.B + (long)z * p.sB;

  f32x4 acc[4][4];
  const f32x4 zero4 = {0.f, 0.f, 0.f, 0.f};
#pragma unroll
  for (int i = 0; i < 4; ++i)
#pragma unroll
    for (int j = 0; j < 4; ++j) acc[i][j] = zero4;

  // staging: 256 threads x 16B = 4KB/issue; 4 issues per 128x64 bf16 tile
  const u16* gA = A  + (size_t)(bm0 + wave*8 + (lane>>3)) * p.lda + (lane&7)*8;
  const u16* gB = Bm + (size_t)(bn0 + wave*8 + (lane>>3)) * p.ldb + (lane&7)*8;
  char* ldsA = smem;
  char* ldsB = smem + 16384;
  char* stA  = ldsA + wave*1024;
  char* stB  = ldsB + wave*1024;

  // fragment offsets: row-major [128][64] bf16, row stride 128B
  // A-frag (16x16x32): row = lane&15, k = (lane>>4)*8 + e
  const int aOff = (wr*64 + (lane&15)) * 128 + (lane>>4)*16;
  const int bOff = (wc*64 + (lane&15)) * 128 + (lane>>4)*16;

  for (int k0 = 0; k0 < p.K; k0 += 64) {
#pragma unroll
    for (int i = 0; i < 4; ++i) {
      gload16(gA + (size_t)i*32*p.lda, stA + i*4096);
      gload16(gB + (size_t)i*32*p.ldb, stB + i*4096);
    }
    gA += 64; gB += 64;
    __syncthreads();
#pragma unroll
    for (int kk = 0; kk < 2; ++kk) {
      bf16x8 av[4], bv[4];
#pragma unroll
      for (int i = 0; i < 4; ++i)
        av[i] = *(const bf16x8*)(ldsA + aOff + i*2048 + kk*64);
#pragma unroll
      for (int j = 0; j < 4; ++j)
        bv[j] = *(const bf16x8*)(ldsB + bOff + j*2048 + kk*64);
#pragma unroll
      for (int i = 0; i < 4; ++i)
#pragma unroll
        for (int j = 0; j < 4; ++j)
          acc[i][j] = __builtin_amdgcn_mfma_f32_16x16x32_bf16(av[i], bv[j], acc[i][j], 0, 0, 0);
    }
    __syncthreads();
  }

  // epilogue: C/D layout col = lane&15, row = (lane>>4)*4 + reg  [m89]
  const int r0 = bm0 + wr*64 + ((lane>>4) << 2);
  const int c0 = bn0 + wc*64 + (lane&15);
#pragma unroll
  for (int i = 0; i < 4; ++i) {
#pragma unroll
    for (int j = 0; j < 4; ++j) {
      const int col = c0 + j*16;
#pragma unroll
      for (int r = 0; r < 4; ++r) {
        const int row = r0 + i*16 + r;
        float v = acc[i][j][r];
        if constexpr (MODE == 0) {
          v += p.bias[col];
          const int which = col / NHD_;
          const int rem = col - which*NHD_;
          const int n = rem / HD_;
          const int h = rem - n*HD_;
          const int bb = row >> 9, s = row & 511;     // local batch within chunk
          const long zz = (long)(bb*NH_ + n);
          if (which == 0)      ((u16*)p.o0)[zz*(long)(S_*HD_) + (long)s*HD_ + h] = f2bf(v);
          else if (which == 1) ((u16*)p.o1)[zz*(long)(S_*HD_) + (long)s*HD_ + h] = f2bf(v);
          else                 ((u16*)p.o2)[zz*(long)(S_*HD_) + (long)h*S_  + s] = f2bf(v);
        } else if constexpr (MODE == 1) {
          ((u16*)p.o0)[(long)z*S_*S_ + (long)row*S_ + col] = f2bf(v * QK_SCALE);
        } else if constexpr (MODE == 2) {
          const int bb = z / NH_, n = z - bb*NH_;
          ((u16*)p.o0)[(long)(bb*S_ + row)*NHD_ + n*HD_ + col] = f2bf(v);
        } else {
          ((float*)p.o0)[(long)row*HD_ + col] = v + p.bias[col];
        }
      }
    }
  }
}

// one wave per row (512 cols, bf16 in/out): +mask, softmax
// maskc already offset to this chunk's first batch
__global__ __launch_bounds__(256)
void softmax_rows(const u16* __restrict__ S, u16* __restrict__ P,
                  const float* __restrict__ maskc) {
  const int wave = threadIdx.x >> 6, lane = threadIdx.x & 63;
  const int rid = blockIdx.x * 4 + wave;          // zloc*512 + q
  const int z = rid >> 9;
  const int b = z / NH_;                          // local batch
  const u16x8 sv = *(const u16x8*)(S + (size_t)rid * S_ + lane*8);
  const float* mrow = maskc + (size_t)b * S_;
  float vals[8];
  float m = -3.4e38f;
#pragma unroll
  for (int j = 0; j < 8; ++j) {
    vals[j] = bf2f(sv[j]) + mrow[lane*8 + j];
    m = fmaxf(m, vals[j]);
  }
#pragma unroll
  for (int o = 32; o > 0; o >>= 1) m = fmaxf(m, __shfl_xor(m, o));
  float sum = 0.f;
#pragma unroll
  for (int j = 0; j < 8; ++j) { vals[j] = __expf(vals[j] - m); sum += vals[j]; }
#pragma unroll
  for (int o = 32; o > 0; o >>= 1) sum += __shfl_xor(sum, o);
  const float inv = 1.0f / sum;
  u16x8 pv;
#pragma unroll
  for (int j = 0; j < 8; ++j) pv[j] = f2bf(vals[j] * inv);
  *(u16x8*)(P + (size_t)rid * S_ + lane*8) = pv;
}

__global__ __launch_bounds__(256)
void cvt_bf16(const float4* __restrict__ in, ushort4* __restrict__ out, int n4) {
  const int i = blockIdx.x * 256 + threadIdx.x;
  if (i >= n4) return;
  const float4 v = in[i];
  ushort4 o;
  o.x = f2bf(v.x); o.y = f2bf(v.y); o.z = f2bf(v.z); o.w = f2bf(v.w);
  out[i] = o;
}

extern "C" void kernel_launch(void* const* d_in, const int* in_sizes, int n_in,
                              void* d_out, int out_size, void* d_ws, size_t ws_size,
                              hipStream_t stream) {
  const float* x     = (const float*)d_in[0];
  const float* mask  = (const float*)d_in[1];
  const float* w_qkv = (const float*)d_in[2];
  const float* b_qkv = (const float*)d_in[3];
  const float* w_o   = (const float*)d_in[4];
  const float* b_o   = (const float*)d_in[5];
  float* out = (float*)d_out;

  // ---- adaptive batch-chunked workspace layout (bytes) ----
  // fixed:   wqb 42,467,328 | wob 14,155,776            (= 56,623,104)
  // per-bc:  xb bc*786,432 | Q,K,Vt bc*9,437,184 each | S bc*6,291,456
  //          P aliases K (dead after scores), H aliases Q (dead after scores)
  // total(bc) = 56,623,104 + bc*35,389,440
  int bc = 0;
  for (int c = 8; c >= 1; c >>= 1)
    if (56623104UL + (unsigned long)c*35389440UL <= ws_size) { bc = c; break; }
  if (bc == 0) return;  // < 92 MB scratch: handled next round if it happens

  char* ws = (char*)d_ws;
  u16* wqb = (u16*)(ws);
  u16* wob = (u16*)(ws + 42467328L);
  u16* xb  = (u16*)(ws + 56623104L);
  long off = 56623104L + (long)bc*786432L;
  u16* Q   = (u16*)(ws + off);  off += (long)bc*9437184L;
  u16* Kb  = (u16*)(ws + off);  off += (long)bc*9437184L;
  u16* Vt  = (u16*)(ws + off);  off += (long)bc*9437184L;
  u16* Sb  = (u16*)(ws + off);
  u16* Pb  = Kb;   // alias
  u16* H   = Q;    // alias

  cvt_bf16<<<dim3(D3_*HD_/4/256), dim3(256), 0, stream>>>((const float4*)w_qkv, (ushort4*)wqb, D3_*HD_/4);
  cvt_bf16<<<dim3(HD_*NHD_/4/256), dim3(256), 0, stream>>>((const float4*)w_o, (ushort4*)wob, HD_*NHD_/4);

  const int nchunks = B_ / bc;
  const int rows_c = bc * S_;          // rows per chunk
  const int zc = bc * NH_;             // heads per chunk

  for (int c = 0; c < nchunks; ++c) {
    const long row0 = (long)c * rows_c;

    cvt_bf16<<<dim3(rows_c*HD_/4/256), dim3(256), 0, stream>>>(
        (const float4*)(x + row0*HD_), (ushort4*)xb, rows_c*HD_/4);

    GP p1; p1.A = xb; p1.B = wqb; p1.K = HD_; p1.lda = HD_; p1.ldb = HD_;
    p1.sA = 0; p1.sB = 0; p1.o0 = Q; p1.o1 = Kb; p1.o2 = Vt; p1.bias = b_qkv;
    gemm_bt<0><<<dim3(D3_/128, rows_c/128, 1), dim3(256), 0, stream>>>(p1);

    GP p2; p2.A = Q; p2.B = Kb; p2.K = HD_; p2.lda = HD_; p2.ldb = HD_;
    p2.sA = (long)S_*HD_; p2.sB = (long)S_*HD_;
    p2.o0 = Sb; p2.o1 = nullptr; p2.o2 = nullptr; p2.bias = nullptr;
    gemm_bt<1><<<dim3(S_/128, S_/128, zc), dim3(256), 0, stream>>>(p2);

    softmax_rows<<<dim3(zc*S_/4), dim3(256), 0, stream>>>(Sb, Pb, mask + (long)c*bc*S_);

    GP p3; p3.A = Pb; p3.B = Vt; p3.K = S_; p3.lda = S_; p3.ldb = S_;
    p3.sA = (long)S_*S_; p3.sB = (long)S_*HD_;
    p3.o0 = H; p3.o1 = nullptr; p3.o2 = nullptr; p3.bias = nullptr;
    gemm_bt<2><<<dim3(HD_/128, S_/128, zc), dim3(256), 0, stream>>>(p3);

    GP p4; p4.A = H; p4.B = wob; p4.K = NHD_; p4.lda = NHD_; p4.ldb = NHD_;
    p4.sA = 0; p4.sB = 0; p4.o0 = out + row0*HD_; p4.o1 = nullptr; p4.o2 = nullptr; p4.bias = b_o;
    gemm_bt<3><<<dim3(HD_/128, rows_c/128, 1), dim3(256), 0, stream>>>(p4);
  }
}

// Round 3
// 741.628 us; speedup vs baseline: 1.0953x; 1.0953x over previous
//
#include <hip/hip_runtime.h>
#include <hip/hip_bf16.h>
#include <stdint.h>

#define AS1 __attribute__((address_space(1)))
#define AS3 __attribute__((address_space(3)))

typedef __attribute__((ext_vector_type(8))) __bf16 bf16x8;
typedef __attribute__((ext_vector_type(4))) float f32x4;
typedef unsigned short u16;
typedef __attribute__((ext_vector_type(8))) unsigned short u16x8;

// ---- problem sizes (fixed for this module) ----
#define B_    8
#define S_    512
#define NH_   12
#define HD_   768
#define NHD_  (NH_*HD_)     // 9216
#define D3_   (3*NHD_)      // 27648
#define QK_SCALE 0.03608439182435161f   // 1/sqrt(768)

__device__ __forceinline__ u16 f2bf(float x) {
  union { float f; unsigned u; } a; a.f = x;
  unsigned r = a.u + 0x7fffu + ((a.u >> 16) & 1u);   // RNE
  return (u16)(r >> 16);
}
__device__ __forceinline__ float bf2f(u16 x) {
  union { unsigned u; float f; } a; a.u = ((unsigned)x) << 16; return a.f;
}

__device__ __forceinline__ void gload16(const void* g, void* l) {
  // async global->LDS; LDS dest = wave-uniform base + lane*16, global src per-lane
  __builtin_amdgcn_global_load_lds((const AS1 void*)g, (AS3 void*)l, 16, 0, 0);
}

// ============================================================================
// QKV GEMM: 256x256 tile, BK=64, 8 waves (2M x 4N), counted-vmcnt double buffer,
// T2 XOR swizzle (pre-swizzled global source + swizzled ds_read), XCD swizzle.
// A = xb (rows_c x 768), B = wqb (27648 x 768), C = A*B^T scattered to Q/K/Vt.
// ============================================================================
__global__ __launch_bounds__(512, 2)
void qkv_gemm256(const u16* __restrict__ A, const u16* __restrict__ Bw,
                 const float* __restrict__ bias,
                 u16* __restrict__ Q, u16* __restrict__ Kb, u16* __restrict__ Vt,
                 int Mt) {
  extern __shared__ char smem[];        // 128 KB: A[2][256][128B] | B[2][256][128B]
  char* ldsA = smem;
  char* ldsB = smem + 65536;
  const int tid = threadIdx.x, wid = tid >> 6, lane = tid & 63;
  const int wm = wid >> 2, wn = wid & 3;

  // bijective XCD swizzle (nwg = 108*Mt, always divisible by 8 here)
  const int nwg = gridDim.x, cpx = nwg >> 3;
  const int bid = blockIdx.x;
  const int tile = (bid & 7) * cpx + (bid >> 3);
  const int m_idx = tile % Mt, n_idx = tile / Mt;
  const long bm0 = (long)m_idx * 256, bn0 = (long)n_idx * 256;

  // staging: per issue, 512 threads x 16B = 64 rows of 128B (linear LDS dest).
  // source col pre-swizzled so logical(row,c) sits at physical(row, c^(row&7)) [16B units]
  const int srow = tid >> 3;                                 // 0..63
  const int scol = ((tid & 7) ^ ((tid >> 3) & 7)) * 8;       // elements
  const u16* gA = A  + (bm0 + srow) * HD_ + scol;
  const u16* gB = Bw + (bn0 + srow) * HD_ + scol;
  const int ldsOff = wid * 1024;

  f32x4 acc[8][4];
  const f32x4 zero4 = {0.f, 0.f, 0.f, 0.f};
#pragma unroll
  for (int i = 0; i < 8; ++i)
#pragma unroll
    for (int j = 0; j < 4; ++j) acc[i][j] = zero4;

  auto stage = [&](int t, int buf) {
    const u16* ga = gA + t * 64;
    const u16* gb = gB + t * 64;
    char* la = ldsA + buf * 32768 + ldsOff;
    char* lb = ldsB + buf * 32768 + ldsOff;
#pragma unroll
    for (int i = 0; i < 4; ++i) {
      gload16(ga + (size_t)i * 64 * HD_, la + i * 8192);
      gload16(gb + (size_t)i * 64 * HD_, lb + i * 8192);
    }
  };

  const int rA0 = wm * 128 + (lane & 15);
  const int rB0 = wn * 64 + (lane & 15);
  const int cswz = lane & 7;   // == row&7 for all fragment rows (bases are x16)

  stage(0, 0);
  stage(1, 1);

  for (int t = 0; t < 12; ++t) {   // K = 768 = 12 * 64
    // wait for tile t's 8 loads (leave tile t+1's 8 in flight); tail drains
    if (t < 11) asm volatile("s_waitcnt vmcnt(8)" ::: "memory");
    else        asm volatile("s_waitcnt vmcnt(0)" ::: "memory");
    __builtin_amdgcn_s_barrier();
    asm volatile("" ::: "memory");   // fence: no LDS read hoists above barrier

    const char* bufA = ldsA + (t & 1) * 32768;
    const char* bufB = ldsB + (t & 1) * 32768;
#pragma unroll
    for (int ks = 0; ks < 2; ++ks) {
      const int c16 = (((ks << 2) + (lane >> 4)) ^ cswz) << 4;  // swizzled byte col
      bf16x8 bv[4];
#pragma unroll
      for (int ni = 0; ni < 4; ++ni)
        bv[ni] = *(const bf16x8*)(bufB + (rB0 + ni * 16) * 128 + c16);
#pragma unroll
      for (int mi = 0; mi < 8; ++mi) {
        const bf16x8 av = *(const bf16x8*)(bufA + (rA0 + mi * 16) * 128 + c16);
#pragma unroll
        for (int ni = 0; ni < 4; ++ni)
          acc[mi][ni] = __builtin_amdgcn_mfma_f32_16x16x32_bf16(av, bv[ni], acc[mi][ni], 0, 0, 0);
      }
    }
    __builtin_amdgcn_s_barrier();    // all waves done reading buf (t&1)
    asm volatile("" ::: "memory");
    if (t + 2 < 12) stage(t + 2, t & 1);   // overwrite now-dead buffer; lands by vmcnt(8) at t+2
  }

  // epilogue: C/D layout col = lane&15, row = (lane>>4)*4 + reg
  const int r0 = (int)bm0 + wm * 128 + ((lane >> 4) << 2);
  const int c0 = (int)bn0 + wn * 64 + (lane & 15);
#pragma unroll
  for (int mi = 0; mi < 8; ++mi) {
#pragma unroll
    for (int ni = 0; ni < 4; ++ni) {
      const int col = c0 + ni * 16;
      const int which = col / NHD_;
      const int rem = col - which * NHD_;
      const int n = rem / HD_;
      const int h = rem - n * HD_;
      const float bs = bias[col];
#pragma unroll
      for (int r = 0; r < 4; ++r) {
        const int row = r0 + mi * 16 + r;     // chunk-local row
        const float v = acc[mi][ni][r] + bs;
        const int bb = row >> 9, s = row & 511;
        const long zz = (long)(bb * NH_ + n);
        if (which == 0)      Q [zz * (long)(S_*HD_) + (long)s * HD_ + h] = f2bf(v);
        else if (which == 1) Kb[zz * (long)(S_*HD_) + (long)s * HD_ + h] = f2bf(v);
        else                 Vt[zz * (long)(S_*HD_) + (long)h * S_  + s] = f2bf(v);
      }
    }
  }
}

// ============================================================================
// 128x128 GEMM (proven path) for scores / AV / split-K out-proj
// ============================================================================
struct GP {
  const u16* A;   // M x K row-major, lda
  const u16* B;   // N x K row-major, ldb  (C = A * B^T)
  int K, lda, ldb;
  long sA, sB;    // per-blockIdx.z element strides
  void* o0;
  const float* bias;
};

// MODE 1: scores -> S bf16 (z,row,col), * QK_SCALE
// MODE 2: AV     -> H bf16 at (bloc*512+row)*9216 + n*768 + col
// MODE 3: out-proj chunk -> atomicAdd into fp32 out (bias pre-filled)
template<int MODE>
__global__ __launch_bounds__(256)
void gemm_bt(GP p) {
  __shared__ __align__(16) char smemS[32768];
  const int tid  = threadIdx.x;
  const int wave = tid >> 6, lane = tid & 63;
  const int wr = wave >> 1, wc = wave & 1;
  const int bm0 = blockIdx.y * 128;
  const int bn0 = blockIdx.x * 128;
  const int z   = blockIdx.z;

  const u16* A  = p.A + (long)z * p.sA;
  const u16* Bm = p.B + (long)z * p.sB;

  f32x4 acc[4][4];
  const f32x4 zero4 = {0.f, 0.f, 0.f, 0.f};
#pragma unroll
  for (int i = 0; i < 4; ++i)
#pragma unroll
    for (int j = 0; j < 4; ++j) acc[i][j] = zero4;

  const u16* gA = A  + (size_t)(bm0 + wave*8 + (lane>>3)) * p.lda + (lane&7)*8;
  const u16* gB = Bm + (size_t)(bn0 + wave*8 + (lane>>3)) * p.ldb + (lane&7)*8;
  char* ldsA = smemS;
  char* ldsB = smemS + 16384;
  char* stA  = ldsA + wave*1024;
  char* stB  = ldsB + wave*1024;

  const int aOff = (wr*64 + (lane&15)) * 128 + (lane>>4)*16;
  const int bOff = (wc*64 + (lane&15)) * 128 + (lane>>4)*16;

  for (int k0 = 0; k0 < p.K; k0 += 64) {
#pragma unroll
    for (int i = 0; i < 4; ++i) {
      gload16(gA + (size_t)i*32*p.lda, stA + i*4096);
      gload16(gB + (size_t)i*32*p.ldb, stB + i*4096);
    }
    gA += 64; gB += 64;
    __syncthreads();
#pragma unroll
    for (int kk = 0; kk < 2; ++kk) {
      bf16x8 av[4], bv[4];
#pragma unroll
      for (int i = 0; i < 4; ++i)
        av[i] = *(const bf16x8*)(ldsA + aOff + i*2048 + kk*64);
#pragma unroll
      for (int j = 0; j < 4; ++j)
        bv[j] = *(const bf16x8*)(ldsB + bOff + j*2048 + kk*64);
#pragma unroll
      for (int i = 0; i < 4; ++i)
#pragma unroll
        for (int j = 0; j < 4; ++j)
          acc[i][j] = __builtin_amdgcn_mfma_f32_16x16x32_bf16(av[i], bv[j], acc[i][j], 0, 0, 0);
    }
    __syncthreads();
  }

  const int r0 = bm0 + wr*64 + ((lane>>4) << 2);
  const int c0 = bn0 + wc*64 + (lane&15);
#pragma unroll
  for (int i = 0; i < 4; ++i) {
#pragma unroll
    for (int j = 0; j < 4; ++j) {
      const int col = c0 + j*16;
#pragma unroll
      for (int r = 0; r < 4; ++r) {
        const int row = r0 + i*16 + r;
        const float v = acc[i][j][r];
        if constexpr (MODE == 1) {
          ((u16*)p.o0)[(long)z*S_*S_ + (long)row*S_ + col] = f2bf(v * QK_SCALE);
        } else if constexpr (MODE == 2) {
          const int bb = z / NH_, n = z - bb*NH_;
          ((u16*)p.o0)[(long)(bb*S_ + row)*NHD_ + n*HD_ + col] = f2bf(v);
        } else {
          atomicAdd(&((float*)p.o0)[(long)row*HD_ + col], v);
        }
      }
    }
  }
}

// one wave per row (512 cols, bf16 in/out): +mask, softmax
__global__ __launch_bounds__(256)
void softmax_rows(const u16* __restrict__ S, u16* __restrict__ P,
                  const float* __restrict__ maskc) {
  const int wave = threadIdx.x >> 6, lane = threadIdx.x & 63;
  const int rid = blockIdx.x * 4 + wave;
  const int z = rid >> 9;
  const int b = z / NH_;
  const u16x8 sv = *(const u16x8*)(S + (size_t)rid * S_ + lane*8);
  const float* mrow = maskc + (size_t)b * S_;
  float vals[8];
  float m = -3.4e38f;
#pragma unroll
  for (int j = 0; j < 8; ++j) {
    vals[j] = bf2f(sv[j]) + mrow[lane*8 + j];
    m = fmaxf(m, vals[j]);
  }
#pragma unroll
  for (int o = 32; o > 0; o >>= 1) m = fmaxf(m, __shfl_xor(m, o));
  float sum = 0.f;
#pragma unroll
  for (int j = 0; j < 8; ++j) { vals[j] = __expf(vals[j] - m); sum += vals[j]; }
#pragma unroll
  for (int o = 32; o > 0; o >>= 1) sum += __shfl_xor(sum, o);
  const float inv = 1.0f / sum;
  u16x8 pv;
#pragma unroll
  for (int j = 0; j < 8; ++j) pv[j] = f2bf(vals[j] * inv);
  *(u16x8*)(P + (size_t)rid * S_ + lane*8) = pv;
}

__global__ __launch_bounds__(256)
void cvt_bf16(const float4* __restrict__ in, ushort4* __restrict__ out, int n4) {
  const int i = blockIdx.x * 256 + threadIdx.x;
  if (i >= n4) return;
  const float4 v = in[i];
  ushort4 o;
  o.x = f2bf(v.x); o.y = f2bf(v.y); o.z = f2bf(v.z); o.w = f2bf(v.w);
  out[i] = o;
}

// out[row][col] = b_o[col] (fp32), vectorized; n4 = rows*768/4
__global__ __launch_bounds__(256)
void init_out_bias(float4* __restrict__ out, const float* __restrict__ b, int n4) {
  const int i = blockIdx.x * 256 + threadIdx.x;
  if (i >= n4) return;
  const int c = (i * 4) % HD_;
  float4 v; v.x = b[c]; v.y = b[c+1]; v.z = b[c+2]; v.w = b[c+3];
  out[i] = v;
}

extern "C" void kernel_launch(void* const* d_in, const int* in_sizes, int n_in,
                              void* d_out, int out_size, void* d_ws, size_t ws_size,
                              hipStream_t stream) {
  const float* x     = (const float*)d_in[0];
  const float* mask  = (const float*)d_in[1];
  const float* w_qkv = (const float*)d_in[2];
  const float* b_qkv = (const float*)d_in[3];
  const float* w_o   = (const float*)d_in[4];
  const float* b_o   = (const float*)d_in[5];
  float* out = (float*)d_out;

  // adaptive batch-chunked workspace (same layout as round 2)
  int bc = 0;
  for (int c = 8; c >= 1; c >>= 1)
    if (56623104UL + (unsigned long)c*35389440UL <= ws_size) { bc = c; break; }
  if (bc == 0) return;

  char* ws = (char*)d_ws;
  u16* wqb = (u16*)(ws);
  u16* wob = (u16*)(ws + 42467328L);
  u16* xb  = (u16*)(ws + 56623104L);
  long off = 56623104L + (long)bc*786432L;
  u16* Q   = (u16*)(ws + off);  off += (long)bc*9437184L;
  u16* Kb  = (u16*)(ws + off);  off += (long)bc*9437184L;
  u16* Vt  = (u16*)(ws + off);  off += (long)bc*9437184L;
  u16* Sb  = (u16*)(ws + off);
  u16* Pb  = Kb;   // alias
  u16* H   = Q;    // alias

  cvt_bf16<<<dim3(D3_*HD_/4/256), dim3(256), 0, stream>>>((const float4*)w_qkv, (ushort4*)wqb, D3_*HD_/4);
  cvt_bf16<<<dim3(HD_*NHD_/4/256), dim3(256), 0, stream>>>((const float4*)w_o, (ushort4*)wob, HD_*NHD_/4);

  const int nchunks = B_ / bc;
  const int rows_c = bc * S_;
  const int zc = bc * NH_;
  const int Mt = rows_c / 256;

  for (int c = 0; c < nchunks; ++c) {
    const long row0 = (long)c * rows_c;

    cvt_bf16<<<dim3(rows_c*HD_/4/256), dim3(256), 0, stream>>>(
        (const float4*)(x + row0*HD_), (ushort4*)xb, rows_c*HD_/4);

    qkv_gemm256<<<dim3((D3_/256) * Mt), dim3(512), 131072, stream>>>(
        xb, wqb, b_qkv, Q, Kb, Vt, Mt);

    GP p2; p2.A = Q; p2.B = Kb; p2.K = HD_; p2.lda = HD_; p2.ldb = HD_;
    p2.sA = (long)S_*HD_; p2.sB = (long)S_*HD_;
    p2.o0 = Sb; p2.bias = nullptr;
    gemm_bt<1><<<dim3(S_/128, S_/128, zc), dim3(256), 0, stream>>>(p2);

    softmax_rows<<<dim3(zc*S_/4), dim3(256), 0, stream>>>(Sb, Pb, mask + (long)c*bc*S_);

    GP p3; p3.A = Pb; p3.B = Vt; p3.K = S_; p3.lda = S_; p3.ldb = S_;
    p3.sA = (long)S_*S_; p3.sB = (long)S_*HD_;
    p3.o0 = H; p3.bias = nullptr;
    gemm_bt<2><<<dim3(HD_/128, S_/128, zc), dim3(256), 0, stream>>>(p3);

    // out projection: bias init + split-K(4) accumulate
    init_out_bias<<<dim3(rows_c*HD_/4/256), dim3(256), 0, stream>>>(
        (float4*)(out + row0*HD_), b_o, rows_c*HD_/4);
    GP p4; p4.A = H; p4.B = wob; p4.K = NHD_/4; p4.lda = NHD_; p4.ldb = NHD_;
    p4.sA = NHD_/4; p4.sB = NHD_/4;   // z indexes the K-chunk
    p4.o0 = out + row0*HD_; p4.bias = nullptr;
    gemm_bt<3><<<dim3(HD_/128, rows_c/128, 4), dim3(256), 0, stream>>>(p4);
  }
}

// Round 4
// 723.282 us; speedup vs baseline: 1.1230x; 1.0254x over previous
//
#include <hip/hip_runtime.h>
#include <hip/hip_bf16.h>
#include <stdint.h>

#define AS1 __attribute__((address_space(1)))
#define AS3 __attribute__((address_space(3)))

typedef __attribute__((ext_vector_type(8))) __bf16 bf16x8;
typedef __attribute__((ext_vector_type(4))) float f32x4;
typedef unsigned short u16;
typedef __attribute__((ext_vector_type(8))) unsigned short u16x8;

// ---- problem sizes (fixed for this module) ----
#define B_    8
#define S_    512
#define NH_   12
#define HD_   768
#define NHD_  (NH_*HD_)     // 9216
#define D3_   (3*NHD_)      // 27648
#define QK_SCALE 0.03608439182435161f   // 1/sqrt(768)

__device__ __forceinline__ u16 f2bf(float x) {
  union { float f; unsigned u; } a; a.f = x;
  unsigned r = a.u + 0x7fffu + ((a.u >> 16) & 1u);   // RNE
  return (u16)(r >> 16);
}
__device__ __forceinline__ float bf2f(u16 x) {
  union { unsigned u; float f; } a; a.u = ((unsigned)x) << 16; return a.f;
}

__device__ __forceinline__ void gload16(const void* g, void* l) {
  // async global->LDS; LDS dest = wave-uniform base + lane*16, global src per-lane
  __builtin_amdgcn_global_load_lds((const AS1 void*)g, (AS3 void*)l, 16, 0, 0);
}

// ============================================================================
// QKV GEMM: 256x256 tile, BK=32, 8 waves (2M x 4N).
// 4 LDS buffers (4 x 32KB), prefetch distance 2, counted vmcnt(8) -- never 0
// in steady state; ONE barrier per K-tile. XOR swizzle on 64B rows:
// phys_col16 = logical_col16 ^ ((row>>1)&3)  -> 2-way max (free).
// Ledger: before wait at tile t, outstanding = stage(t,t+1,t+2) = 12 loads;
// vmcnt(8) drains exactly tile t. Tail: vmcnt(4), vmcnt(0).
// Race: stage(t+2) overwrites buf((t-2)&3); barrier(t-1) passage implies all
// waves finished compute(t-2). Single barrier per tile is sufficient.
// ============================================================================
template<int NT>   // K = NT*32
__global__ __launch_bounds__(512, 2)
void qkv_gemm256(const u16* __restrict__ A, const u16* __restrict__ Bw,
                 const float* __restrict__ bias,
                 u16* __restrict__ Q, u16* __restrict__ Kb, u16* __restrict__ Vt,
                 int Mt) {
  __shared__ __align__(16) char smem[131072];   // 4 x (A 16KB | B 16KB)
  const int tid = threadIdx.x, wid = tid >> 6, lane = tid & 63;
  const int wm = wid >> 2, wn = wid & 3;

  // bijective XCD swizzle (nwg divisible by 8 for all bc in {1,2,4,8})
  const int nwg = gridDim.x, cpx = nwg >> 3;
  const int bid = blockIdx.x;
  const int tile = (bid & 7) * cpx + (bid >> 3);
  const int m_idx = tile % Mt, n_idx = tile / Mt;
  const long bm0 = (long)m_idx * 256, bn0 = (long)n_idx * 256;

  // staging: each wave stages 32 rows of A and 32 rows of B per tile
  // (2 issues each of 16 rows x 64B). Source pre-swizzled so LDS linear write
  // lands logical(row,c) at physical slot c ^ ((row>>1)&3) [16B units].
  const int srow  = wid * 32 + (lane >> 2);                 // A/B row (+16 for issue 1)
  const int scol  = ((lane & 3) ^ ((lane >> 3) & 3)) * 8;   // element col in k-tile
  const u16* gAl = A  + (bm0 + srow) * HD_ + scol;
  const u16* gBl = Bw + (bn0 + srow) * HD_ + scol;
  const int stOff = wid * 2048;

  f32x4 acc[8][4];
  const f32x4 zero4 = {0.f, 0.f, 0.f, 0.f};
#pragma unroll
  for (int i = 0; i < 8; ++i)
#pragma unroll
    for (int j = 0; j < 4; ++j) acc[i][j] = zero4;

  auto stage = [&](int t) {
    char* base = smem + (t & 3) * 32768;
    const u16* ga = gAl + t * 32;
    const u16* gb = gBl + t * 32;
    gload16(ga,            base + stOff);
    gload16(ga + 16 * HD_, base + stOff + 1024);
    gload16(gb,            base + 16384 + stOff);
    gload16(gb + 16 * HD_, base + 16384 + stOff + 1024);
  };

  // fragment reads: row = <base> + (lane&15), logical col16 = lane>>4,
  // physical col16 = (lane>>4) ^ ((row>>1)&3) = (lane>>4) ^ ((lane>>1)&3)
  const int rswz  = (((lane >> 4) ^ ((lane >> 1) & 3)) << 4);
  const int aBase = (wm * 128 + (lane & 15)) * 64 + rswz;
  const int bBase = (wn * 64  + (lane & 15)) * 64 + rswz + 16384;

  stage(0);
  stage(1);

#pragma unroll
  for (int t = 0; t < NT; ++t) {
    if (t + 2 < NT) stage(t + 2);
    if (t < NT - 2)       asm volatile("s_waitcnt vmcnt(8)" ::: "memory");
    else if (t == NT - 2) asm volatile("s_waitcnt vmcnt(4)" ::: "memory");
    else                  asm volatile("s_waitcnt vmcnt(0)" ::: "memory");
    __builtin_amdgcn_s_barrier();
    asm volatile("" ::: "memory");   // no LDS read hoists above the barrier

    const char* base = smem + (t & 3) * 32768;
    bf16x8 bv[4];
#pragma unroll
    for (int ni = 0; ni < 4; ++ni)
      bv[ni] = *(const bf16x8*)(base + bBase + ni * 1024);
    bf16x8 av[8];
#pragma unroll
    for (int mi = 0; mi < 8; ++mi)
      av[mi] = *(const bf16x8*)(base + aBase + mi * 1024);

    __builtin_amdgcn_s_setprio(1);
#pragma unroll
    for (int mi = 0; mi < 8; ++mi)
#pragma unroll
      for (int ni = 0; ni < 4; ++ni)
        acc[mi][ni] = __builtin_amdgcn_mfma_f32_16x16x32_bf16(av[mi], bv[ni], acc[mi][ni], 0, 0, 0);
    __builtin_amdgcn_s_setprio(0);
  }

  // epilogue: C/D layout col = lane&15, row = (lane>>4)*4 + reg
  const int r0 = (int)bm0 + wm * 128 + ((lane >> 4) << 2);
  const int c0 = (int)bn0 + wn * 64 + (lane & 15);
#pragma unroll
  for (int mi = 0; mi < 8; ++mi) {
#pragma unroll
    for (int ni = 0; ni < 4; ++ni) {
      const int col = c0 + ni * 16;
      const int which = col / NHD_;
      const int rem = col - which * NHD_;
      const int n = rem / HD_;
      const int h = rem - n * HD_;
      const float bs = bias[col];
#pragma unroll
      for (int r = 0; r < 4; ++r) {
        const int row = r0 + mi * 16 + r;     // chunk-local row
        const float v = acc[mi][ni][r] + bs;
        const int bb = row >> 9, s = row & 511;
        const long zz = (long)(bb * NH_ + n);
        if (which == 0)      Q [zz * (long)(S_*HD_) + (long)s * HD_ + h] = f2bf(v);
        else if (which == 1) Kb[zz * (long)(S_*HD_) + (long)s * HD_ + h] = f2bf(v);
        else                 Vt[zz * (long)(S_*HD_) + (long)h * S_  + s] = f2bf(v);
      }
    }
  }
}

// ============================================================================
// 128x128 GEMM (proven path) for scores / AV / split-K out-proj
// ============================================================================
struct GP {
  const u16* A;   // M x K row-major, lda
  const u16* B;   // N x K row-major, ldb  (C = A * B^T)
  int K, lda, ldb;
  long sA, sB;    // per-blockIdx.z element strides
  void* o0;
  const float* bias;
};

// MODE 1: scores -> S bf16 (z,row,col), * QK_SCALE
// MODE 2: AV     -> H bf16 at (bloc*512+row)*9216 + n*768 + col
// MODE 3: out-proj chunk -> atomicAdd into fp32 out (bias pre-filled)
template<int MODE>
__global__ __launch_bounds__(256)
void gemm_bt(GP p) {
  __shared__ __align__(16) char smemS[32768];
  const int tid  = threadIdx.x;
  const int wave = tid >> 6, lane = tid & 63;
  const int wr = wave >> 1, wc = wave & 1;
  const int bm0 = blockIdx.y * 128;
  const int bn0 = blockIdx.x * 128;
  const int z   = blockIdx.z;

  const u16* A  = p.A + (long)z * p.sA;
  const u16* Bm = p.B + (long)z * p.sB;

  f32x4 acc[4][4];
  const f32x4 zero4 = {0.f, 0.f, 0.f, 0.f};
#pragma unroll
  for (int i = 0; i < 4; ++i)
#pragma unroll
    for (int j = 0; j < 4; ++j) acc[i][j] = zero4;

  const u16* gA = A  + (size_t)(bm0 + wave*8 + (lane>>3)) * p.lda + (lane&7)*8;
  const u16* gB = Bm + (size_t)(bn0 + wave*8 + (lane>>3)) * p.ldb + (lane&7)*8;
  char* ldsA = smemS;
  char* ldsB = smemS + 16384;
  char* stA  = ldsA + wave*1024;
  char* stB  = ldsB + wave*1024;

  const int aOff = (wr*64 + (lane&15)) * 128 + (lane>>4)*16;
  const int bOff = (wc*64 + (lane&15)) * 128 + (lane>>4)*16;

  for (int k0 = 0; k0 < p.K; k0 += 64) {
#pragma unroll
    for (int i = 0; i < 4; ++i) {
      gload16(gA + (size_t)i*32*p.lda, stA + i*4096);
      gload16(gB + (size_t)i*32*p.ldb, stB + i*4096);
    }
    gA += 64; gB += 64;
    __syncthreads();
#pragma unroll
    for (int kk = 0; kk < 2; ++kk) {
      bf16x8 av[4], bv[4];
#pragma unroll
      for (int i = 0; i < 4; ++i)
        av[i] = *(const bf16x8*)(ldsA + aOff + i*2048 + kk*64);
#pragma unroll
      for (int j = 0; j < 4; ++j)
        bv[j] = *(const bf16x8*)(ldsB + bOff + j*2048 + kk*64);
#pragma unroll
      for (int i = 0; i < 4; ++i)
#pragma unroll
        for (int j = 0; j < 4; ++j)
          acc[i][j] = __builtin_amdgcn_mfma_f32_16x16x32_bf16(av[i], bv[j], acc[i][j], 0, 0, 0);
    }
    __syncthreads();
  }

  const int r0 = bm0 + wr*64 + ((lane>>4) << 2);
  const int c0 = bn0 + wc*64 + (lane&15);
#pragma unroll
  for (int i = 0; i < 4; ++i) {
#pragma unroll
    for (int j = 0; j < 4; ++j) {
      const int col = c0 + j*16;
#pragma unroll
      for (int r = 0; r < 4; ++r) {
        const int row = r0 + i*16 + r;
        const float v = acc[i][j][r];
        if constexpr (MODE == 1) {
          ((u16*)p.o0)[(long)z*S_*S_ + (long)row*S_ + col] = f2bf(v * QK_SCALE);
        } else if constexpr (MODE == 2) {
          const int bb = z / NH_, n = z - bb*NH_;
          ((u16*)p.o0)[(long)(bb*S_ + row)*NHD_ + n*HD_ + col] = f2bf(v);
        } else {
          atomicAdd(&((float*)p.o0)[(long)row*HD_ + col], v);
        }
      }
    }
  }
}

// one wave per row (512 cols, bf16 in/out): +mask, softmax
__global__ __launch_bounds__(256)
void softmax_rows(const u16* __restrict__ S, u16* __restrict__ P,
                  const float* __restrict__ maskc) {
  const int wave = threadIdx.x >> 6, lane = threadIdx.x & 63;
  const int rid = blockIdx.x * 4 + wave;
  const int z = rid >> 9;
  const int b = z / NH_;
  const u16x8 sv = *(const u16x8*)(S + (size_t)rid * S_ + lane*8);
  const float* mrow = maskc + (size_t)b * S_;
  float vals[8];
  float m = -3.4e38f;
#pragma unroll
  for (int j = 0; j < 8; ++j) {
    vals[j] = bf2f(sv[j]) + mrow[lane*8 + j];
    m = fmaxf(m, vals[j]);
  }
#pragma unroll
  for (int o = 32; o > 0; o >>= 1) m = fmaxf(m, __shfl_xor(m, o));
  float sum = 0.f;
#pragma unroll
  for (int j = 0; j < 8; ++j) { vals[j] = __expf(vals[j] - m); sum += vals[j]; }
#pragma unroll
  for (int o = 32; o > 0; o >>= 1) sum += __shfl_xor(sum, o);
  const float inv = 1.0f / sum;
  u16x8 pv;
#pragma unroll
  for (int j = 0; j < 8; ++j) pv[j] = f2bf(vals[j] * inv);
  *(u16x8*)(P + (size_t)rid * S_ + lane*8) = pv;
}

__global__ __launch_bounds__(256)
void cvt_bf16(const float4* __restrict__ in, ushort4* __restrict__ out, int n4) {
  const int i = blockIdx.x * 256 + threadIdx.x;
  if (i >= n4) return;
  const float4 v = in[i];
  ushort4 o;
  o.x = f2bf(v.x); o.y = f2bf(v.y); o.z = f2bf(v.z); o.w = f2bf(v.w);
  out[i] = o;
}

// out[row][col] = b_o[col] (fp32), vectorized; n4 = rows*768/4
__global__ __launch_bounds__(256)
void init_out_bias(float4* __restrict__ out, const float* __restrict__ b, int n4) {
  const int i = blockIdx.x * 256 + threadIdx.x;
  if (i >= n4) return;
  const int c = (i * 4) % HD_;
  float4 v; v.x = b[c]; v.y = b[c+1]; v.z = b[c+2]; v.w = b[c+3];
  out[i] = v;
}

extern "C" void kernel_launch(void* const* d_in, const int* in_sizes, int n_in,
                              void* d_out, int out_size, void* d_ws, size_t ws_size,
                              hipStream_t stream) {
  const float* x     = (const float*)d_in[0];
  const float* mask  = (const float*)d_in[1];
  const float* w_qkv = (const float*)d_in[2];
  const float* b_qkv = (const float*)d_in[3];
  const float* w_o   = (const float*)d_in[4];
  const float* b_o   = (const float*)d_in[5];
  float* out = (float*)d_out;

  // adaptive batch-chunked workspace (same layout as round 2/3)
  int bc = 0;
  for (int c = 8; c >= 1; c >>= 1)
    if (56623104UL + (unsigned long)c*35389440UL <= ws_size) { bc = c; break; }
  if (bc == 0) return;

  char* ws = (char*)d_ws;
  u16* wqb = (u16*)(ws);
  u16* wob = (u16*)(ws + 42467328L);
  u16* xb  = (u16*)(ws + 56623104L);
  long off = 56623104L + (long)bc*786432L;
  u16* Q   = (u16*)(ws + off);  off += (long)bc*9437184L;
  u16* Kb  = (u16*)(ws + off);  off += (long)bc*9437184L;
  u16* Vt  = (u16*)(ws + off);  off += (long)bc*9437184L;
  u16* Sb  = (u16*)(ws + off);
  u16* Pb  = Kb;   // alias
  u16* H   = Q;    // alias

  cvt_bf16<<<dim3(D3_*HD_/4/256), dim3(256), 0, stream>>>((const float4*)w_qkv, (ushort4*)wqb, D3_*HD_/4);
  cvt_bf16<<<dim3(HD_*NHD_/4/256), dim3(256), 0, stream>>>((const float4*)w_o, (ushort4*)wob, HD_*NHD_/4);

  const int nchunks = B_ / bc;
  const int rows_c = bc * S_;
  const int zc = bc * NH_;
  const int Mt = rows_c / 256;

  for (int c = 0; c < nchunks; ++c) {
    const long row0 = (long)c * rows_c;

    cvt_bf16<<<dim3(rows_c*HD_/4/256), dim3(256), 0, stream>>>(
        (const float4*)(x + row0*HD_), (ushort4*)xb, rows_c*HD_/4);

    qkv_gemm256<24><<<dim3((D3_/256) * Mt), dim3(512), 0, stream>>>(
        xb, wqb, b_qkv, Q, Kb, Vt, Mt);

    GP p2; p2.A = Q; p2.B = Kb; p2.K = HD_; p2.lda = HD_; p2.ldb = HD_;
    p2.sA = (long)S_*HD_; p2.sB = (long)S_*HD_;
    p2.o0 = Sb; p2.bias = nullptr;
    gemm_bt<1><<<dim3(S_/128, S_/128, zc), dim3(256), 0, stream>>>(p2);

    softmax_rows<<<dim3(zc*S_/4), dim3(256), 0, stream>>>(Sb, Pb, mask + (long)c*bc*S_);

    GP p3; p3.A = Pb; p3.B = Vt; p3.K = S_; p3.lda = S_; p3.ldb = S_;
    p3.sA = (long)S_*S_; p3.sB = (long)S_*HD_;
    p3.o0 = H; p3.bias = nullptr;
    gemm_bt<2><<<dim3(HD_/128, S_/128, zc), dim3(256), 0, stream>>>(p3);

    // out projection: bias init + split-K(4) accumulate
    init_out_bias<<<dim3(rows_c*HD_/4/256), dim3(256), 0, stream>>>(
        (float4*)(out + row0*HD_), b_o, rows_c*HD_/4);
    GP p4; p4.A = H; p4.B = wob; p4.K = NHD_/4; p4.lda = NHD_; p4.ldb = NHD_;
    p4.sA = NHD_/4; p4.sB = NHD_/4;   // z indexes the K-chunk
    p4.o0 = out + row0*HD_; p4.bias = nullptr;
    gemm_bt<3><<<dim3(HD_/128, rows_c/128, 4), dim3(256), 0, stream>>>(p4);
  }
}

// Round 5
// 722.729 us; speedup vs baseline: 1.1239x; 1.0008x over previous
//
#include <hip/hip_runtime.h>
#include <hip/hip_bf16.h>
#include <stdint.h>

#define AS1 __attribute__((address_space(1)))
#define AS3 __attribute__((address_space(3)))

typedef __attribute__((ext_vector_type(8))) __bf16 bf16x8;
typedef __attribute__((ext_vector_type(4))) float f32x4;
typedef unsigned short u16;
typedef __attribute__((ext_vector_type(8))) unsigned short u16x8;

// ---- problem sizes (fixed for this module) ----
#define B_    8
#define S_    512
#define NH_   12
#define HD_   768
#define NHD_  (NH_*HD_)     // 9216
#define D3_   (3*NHD_)      // 27648
#define QK_SCALE 0.03608439182435161f   // 1/sqrt(768)

__device__ __forceinline__ u16 f2bf(float x) {
  union { float f; unsigned u; } a; a.f = x;
  unsigned r = a.u + 0x7fffu + ((a.u >> 16) & 1u);   // RNE
  return (u16)(r >> 16);
}
__device__ __forceinline__ float bf2f(u16 x) {
  union { unsigned u; float f; } a; a.u = ((unsigned)x) << 16; return a.f;
}

__device__ __forceinline__ void gload16(const void* g, void* l) {
  // async global->LDS; LDS dest = wave-uniform base + lane*16, global src per-lane
  __builtin_amdgcn_global_load_lds((const AS1 void*)g, (AS3 void*)l, 16, 0, 0);
}

// ============================================================================
// QKV GEMM: 256x256 tile, BK=32, 8 waves (2M x 4N), 4 LDS buffers (4 x 32KB).
// m201-style per-phase interleave: 2 phases per K-tile, each
//   {ds_reads (quadrant) | 2 gload_lds prefetch -> barrier -> lgkmcnt(0)
//    -> setprio(1) 16xMFMA setprio(0) -> barrier}
// vmcnt ledger (per wave, 4 gloads per staged tile, prefetch distance 2):
//   end of tile t: outstanding = [stage(t+1):4][stage(t+2):4]; vmcnt(4)
//   drains stage(t+1) BEFORE the closing barrier -> all waves' stage(t+1)
//   confirmed before any wave ds_reads buf(t+1). Tail: vmcnt(0) at t=NT-2.
// Race: stage(t+2) overwrites buf((t-2)&3); readers of buf(t-2) finished
// before tile t-2's closing barrier; staging wave passed tile t-1's closing
// barrier since. Safe.
// Swizzle (verified: 0 bank conflicts, round 4): 64B rows, phys_col16 =
// logical_col16 ^ ((row>>1)&3); staging pre-swizzles the global source col.
// ============================================================================
template<int NT>   // K = NT*32
__global__ __launch_bounds__(512, 2)
void qkv_gemm256(const u16* __restrict__ A, const u16* __restrict__ Bw,
                 const float* __restrict__ bias,
                 u16* __restrict__ Q, u16* __restrict__ Kb, u16* __restrict__ Vt,
                 int mtMask, int mtShift) {
  __shared__ __align__(16) char smem[131072];   // 4 x (A 16KB | B 16KB)
  const int tid = threadIdx.x, wid = tid >> 6, lane = tid & 63;
  const int wm = wid >> 2, wn = wid & 3;

  // bijective XCD swizzle (nwg divisible by 8 for all bc in {1,2,4,8})
  const int nwg = gridDim.x, cpx = nwg >> 3;
  const int bid = blockIdx.x;
  const int tile = (bid & 7) * cpx + (bid >> 3);
  const int m_idx = tile & mtMask, n_idx = tile >> mtShift;
  const long bm0 = (long)m_idx * 256, bn0 = (long)n_idx * 256;

  // staging: wave stages rows [wid*32, wid*32+31] of A (phase A) and of B
  // (phase B), 2 gloads each (16 rows x 64B per gload). Source col
  // pre-swizzled so linear LDS write lands logical c at phys c^((row>>1)&3).
  const int srow  = wid * 32 + (lane >> 2);
  const int scol  = ((lane & 3) ^ ((lane >> 3) & 3)) * 8;   // elements
  const u16* gAl = A  + (bm0 + srow) * HD_ + scol;
  const u16* gBl = Bw + (bn0 + srow) * HD_ + scol;
  const int stOff = wid * 2048;

  f32x4 acc[8][4];
  const f32x4 zero4 = {0.f, 0.f, 0.f, 0.f};
#pragma unroll
  for (int i = 0; i < 8; ++i)
#pragma unroll
    for (int j = 0; j < 4; ++j) acc[i][j] = zero4;

  auto stageA = [&](int t) {
    char* base = smem + (t & 3) * 32768;
    const u16* ga = gAl + t * 32;
    gload16(ga,            base + stOff);
    gload16(ga + 16 * HD_, base + stOff + 1024);
  };
  auto stageB = [&](int t) {
    char* base = smem + (t & 3) * 32768 + 16384;
    const u16* gb = gBl + t * 32;
    gload16(gb,            base + stOff);
    gload16(gb + 16 * HD_, base + stOff + 1024);
  };

  // fragment reads: row = base + (lane&15), logical col16 = lane>>4,
  // physical col16 = (lane>>4) ^ ((lane>>1)&3)   [row parity = (lane>>1)&3]
  const int rswz  = (((lane >> 4) ^ ((lane >> 1) & 3)) << 4);
  const int aBase = (wm * 128 + (lane & 15)) * 64 + rswz;
  const int bBase = 16384 + (wn * 64 + (lane & 15)) * 64 + rswz;

  stageA(0); stageB(0);
  stageA(1); stageB(1);
  asm volatile("s_waitcnt vmcnt(4)" ::: "memory");   // stage(0) done
  __builtin_amdgcn_s_barrier();

#pragma unroll
  for (int t = 0; t < NT; ++t) {
    const char* base = smem + (t & 3) * 32768;

    // -------- phase A: quadrant mi 0-3 x ni 0-3 --------
    bf16x8 av[4], bv[4];
#pragma unroll
    for (int mi = 0; mi < 4; ++mi)
      av[mi] = *(const bf16x8*)(base + aBase + mi * 1024);
#pragma unroll
    for (int ni = 0; ni < 4; ++ni)
      bv[ni] = *(const bf16x8*)(base + bBase + ni * 1024);
    if (t + 2 < NT) stageA(t + 2);
    __builtin_amdgcn_s_barrier();
    asm volatile("s_waitcnt lgkmcnt(0)" ::: "memory");
    __builtin_amdgcn_s_setprio(1);
#pragma unroll
    for (int mi = 0; mi < 4; ++mi)
#pragma unroll
      for (int ni = 0; ni < 4; ++ni)
        acc[mi][ni] = __builtin_amdgcn_mfma_f32_16x16x32_bf16(av[mi], bv[ni], acc[mi][ni], 0, 0, 0);
    __builtin_amdgcn_s_setprio(0);
    __builtin_amdgcn_s_barrier();

    // -------- phase B: quadrant mi 4-7 x ni 0-3 (bv reused) --------
    bf16x8 av2[4];
#pragma unroll
    for (int mi = 0; mi < 4; ++mi)
      av2[mi] = *(const bf16x8*)(base + aBase + (mi + 4) * 1024);
    if (t + 2 < NT) stageB(t + 2);
    __builtin_amdgcn_s_barrier();
    asm volatile("s_waitcnt lgkmcnt(0)" ::: "memory");
    __builtin_amdgcn_s_setprio(1);
#pragma unroll
    for (int mi = 0; mi < 4; ++mi)
#pragma unroll
      for (int ni = 0; ni < 4; ++ni)
        acc[mi + 4][ni] = __builtin_amdgcn_mfma_f32_16x16x32_bf16(av2[mi], bv[ni], acc[mi + 4][ni], 0, 0, 0);
    __builtin_amdgcn_s_setprio(0);

    // -------- end of tile: counted drain, then gate for buf(t+1) --------
    if (t < NT - 2) asm volatile("s_waitcnt vmcnt(4)" ::: "memory");
    else            asm volatile("s_waitcnt vmcnt(0)" ::: "memory");
    __builtin_amdgcn_s_barrier();
  }

  // epilogue: C/D layout col = lane&15, row = (lane>>4)*4 + reg
  const int r0 = (int)bm0 + wm * 128 + ((lane >> 4) << 2);
  const int c0 = (int)bn0 + wn * 64 + (lane & 15);
#pragma unroll
  for (int mi = 0; mi < 8; ++mi) {
#pragma unroll
    for (int ni = 0; ni < 4; ++ni) {
      const int col = c0 + ni * 16;
      const int which = col / NHD_;
      const int rem = col - which * NHD_;
      const int n = rem / HD_;
      const int h = rem - n * HD_;
      const float bs = bias[col];
#pragma unroll
      for (int r = 0; r < 4; ++r) {
        const int row = r0 + mi * 16 + r;     // chunk-local row
        const float v = acc[mi][ni][r] + bs;
        const int bb = row >> 9, s = row & 511;
        const long zz = (long)(bb * NH_ + n);
        if (which == 0)      Q [zz * (long)(S_*HD_) + (long)s * HD_ + h] = f2bf(v);
        else if (which == 1) Kb[zz * (long)(S_*HD_) + (long)s * HD_ + h] = f2bf(v);
        else                 Vt[zz * (long)(S_*HD_) + (long)h * S_  + s] = f2bf(v);
      }
    }
  }
}

// ============================================================================
// 128x128 GEMM (proven path) for scores / AV / split-K out-proj
// ============================================================================
struct GP {
  const u16* A;   // M x K row-major, lda
  const u16* B;   // N x K row-major, ldb  (C = A * B^T)
  int K, lda, ldb;
  long sA, sB;    // per-blockIdx.z element strides
  void* o0;
  const float* bias;
};

// MODE 1: scores -> S bf16 (z,row,col), * QK_SCALE
// MODE 2: AV     -> H bf16 at (bloc*512+row)*9216 + n*768 + col
// MODE 3: out-proj chunk -> atomicAdd into fp32 out (bias pre-filled)
template<int MODE>
__global__ __launch_bounds__(256)
void gemm_bt(GP p) {
  __shared__ __align__(16) char smemS[32768];
  const int tid  = threadIdx.x;
  const int wave = tid >> 6, lane = tid & 63;
  const int wr = wave >> 1, wc = wave & 1;
  const int bm0 = blockIdx.y * 128;
  const int bn0 = blockIdx.x * 128;
  const int z   = blockIdx.z;

  const u16* A  = p.A + (long)z * p.sA;
  const u16* Bm = p.B + (long)z * p.sB;

  f32x4 acc[4][4];
  const f32x4 zero4 = {0.f, 0.f, 0.f, 0.f};
#pragma unroll
  for (int i = 0; i < 4; ++i)
#pragma unroll
    for (int j = 0; j < 4; ++j) acc[i][j] = zero4;

  const u16* gA = A  + (size_t)(bm0 + wave*8 + (lane>>3)) * p.lda + (lane&7)*8;
  const u16* gB = Bm + (size_t)(bn0 + wave*8 + (lane>>3)) * p.ldb + (lane&7)*8;
  char* ldsA = smemS;
  char* ldsB = smemS + 16384;
  char* stA  = ldsA + wave*1024;
  char* stB  = ldsB + wave*1024;

  const int aOff = (wr*64 + (lane&15)) * 128 + (lane>>4)*16;
  const int bOff = (wc*64 + (lane&15)) * 128 + (lane>>4)*16;

  for (int k0 = 0; k0 < p.K; k0 += 64) {
#pragma unroll
    for (int i = 0; i < 4; ++i) {
      gload16(gA + (size_t)i*32*p.lda, stA + i*4096);
      gload16(gB + (size_t)i*32*p.ldb, stB + i*4096);
    }
    gA += 64; gB += 64;
    __syncthreads();
#pragma unroll
    for (int kk = 0; kk < 2; ++kk) {
      bf16x8 av[4], bv[4];
#pragma unroll
      for (int i = 0; i < 4; ++i)
        av[i] = *(const bf16x8*)(ldsA + aOff + i*2048 + kk*64);
#pragma unroll
      for (int j = 0; j < 4; ++j)
        bv[j] = *(const bf16x8*)(ldsB + bOff + j*2048 + kk*64);
#pragma unroll
      for (int i = 0; i < 4; ++i)
#pragma unroll
        for (int j = 0; j < 4; ++j)
          acc[i][j] = __builtin_amdgcn_mfma_f32_16x16x32_bf16(av[i], bv[j], acc[i][j], 0, 0, 0);
    }
    __syncthreads();
  }

  const int r0 = bm0 + wr*64 + ((lane>>4) << 2);
  const int c0 = bn0 + wc*64 + (lane&15);
#pragma unroll
  for (int i = 0; i < 4; ++i) {
#pragma unroll
    for (int j = 0; j < 4; ++j) {
      const int col = c0 + j*16;
#pragma unroll
      for (int r = 0; r < 4; ++r) {
        const int row = r0 + i*16 + r;
        const float v = acc[i][j][r];
        if constexpr (MODE == 1) {
          ((u16*)p.o0)[(long)z*S_*S_ + (long)row*S_ + col] = f2bf(v * QK_SCALE);
        } else if constexpr (MODE == 2) {
          const int bb = z / NH_, n = z - bb*NH_;
          ((u16*)p.o0)[(long)(bb*S_ + row)*NHD_ + n*HD_ + col] = f2bf(v);
        } else {
          atomicAdd(&((float*)p.o0)[(long)row*HD_ + col], v);
        }
      }
    }
  }
}

// one wave per row (512 cols, bf16 in/out): +mask, softmax
__global__ __launch_bounds__(256)
void softmax_rows(const u16* __restrict__ S, u16* __restrict__ P,
                  const float* __restrict__ maskc) {
  const int wave = threadIdx.x >> 6, lane = threadIdx.x & 63;
  const int rid = blockIdx.x * 4 + wave;
  const int z = rid >> 9;
  const int b = z / NH_;
  const u16x8 sv = *(const u16x8*)(S + (size_t)rid * S_ + lane*8);
  const float* mrow = maskc + (size_t)b * S_;
  float vals[8];
  float m = -3.4e38f;
#pragma unroll
  for (int j = 0; j < 8; ++j) {
    vals[j] = bf2f(sv[j]) + mrow[lane*8 + j];
    m = fmaxf(m, vals[j]);
  }
#pragma unroll
  for (int o = 32; o > 0; o >>= 1) m = fmaxf(m, __shfl_xor(m, o));
  float sum = 0.f;
#pragma unroll
  for (int j = 0; j < 8; ++j) { vals[j] = __expf(vals[j] - m); sum += vals[j]; }
#pragma unroll
  for (int o = 32; o > 0; o >>= 1) sum += __shfl_xor(sum, o);
  const float inv = 1.0f / sum;
  u16x8 pv;
#pragma unroll
  for (int j = 0; j < 8; ++j) pv[j] = f2bf(vals[j] * inv);
  *(u16x8*)(P + (size_t)rid * S_ + lane*8) = pv;
}

__global__ __launch_bounds__(256)
void cvt_bf16(const float4* __restrict__ in, ushort4* __restrict__ out, int n4) {
  const int i = blockIdx.x * 256 + threadIdx.x;
  if (i >= n4) return;
  const float4 v = in[i];
  ushort4 o;
  o.x = f2bf(v.x); o.y = f2bf(v.y); o.z = f2bf(v.z); o.w = f2bf(v.w);
  out[i] = o;
}

// out[row][col] = b_o[col] (fp32), vectorized; n4 = rows*768/4
__global__ __launch_bounds__(256)
void init_out_bias(float4* __restrict__ out, const float* __restrict__ b, int n4) {
  const int i = blockIdx.x * 256 + threadIdx.x;
  if (i >= n4) return;
  const int c = (i * 4) % HD_;
  float4 v; v.x = b[c]; v.y = b[c+1]; v.z = b[c+2]; v.w = b[c+3];
  out[i] = v;
}

extern "C" void kernel_launch(void* const* d_in, const int* in_sizes, int n_in,
                              void* d_out, int out_size, void* d_ws, size_t ws_size,
                              hipStream_t stream) {
  const float* x     = (const float*)d_in[0];
  const float* mask  = (const float*)d_in[1];
  const float* w_qkv = (const float*)d_in[2];
  const float* b_qkv = (const float*)d_in[3];
  const float* w_o   = (const float*)d_in[4];
  const float* b_o   = (const float*)d_in[5];
  float* out = (float*)d_out;

  // adaptive batch-chunked workspace (same layout as rounds 2-4)
  int bc = 0;
  for (int c = 8; c >= 1; c >>= 1)
    if (56623104UL + (unsigned long)c*35389440UL <= ws_size) { bc = c; break; }
  if (bc == 0) return;

  char* ws = (char*)d_ws;
  u16* wqb = (u16*)(ws);
  u16* wob = (u16*)(ws + 42467328L);
  u16* xb  = (u16*)(ws + 56623104L);
  long off = 56623104L + (long)bc*786432L;
  u16* Q   = (u16*)(ws + off);  off += (long)bc*9437184L;
  u16* Kb  = (u16*)(ws + off);  off += (long)bc*9437184L;
  u16* Vt  = (u16*)(ws + off);  off += (long)bc*9437184L;
  u16* Sb  = (u16*)(ws + off);
  u16* Pb  = Kb;   // alias
  u16* H   = Q;    // alias

  cvt_bf16<<<dim3(D3_*HD_/4/256), dim3(256), 0, stream>>>((const float4*)w_qkv, (ushort4*)wqb, D3_*HD_/4);
  cvt_bf16<<<dim3(HD_*NHD_/4/256), dim3(256), 0, stream>>>((const float4*)w_o, (ushort4*)wob, HD_*NHD_/4);

  const int nchunks = B_ / bc;
  const int rows_c = bc * S_;
  const int zc = bc * NH_;
  const int Mt = rows_c / 256;           // in {2,4,8,16}
  const int mtShift = __builtin_ctz(Mt);

  for (int c = 0; c < nchunks; ++c) {
    const long row0 = (long)c * rows_c;

    cvt_bf16<<<dim3(rows_c*HD_/4/256), dim3(256), 0, stream>>>(
        (const float4*)(x + row0*HD_), (ushort4*)xb, rows_c*HD_/4);

    qkv_gemm256<24><<<dim3((D3_/256) * Mt), dim3(512), 0, stream>>>(
        xb, wqb, b_qkv, Q, Kb, Vt, Mt - 1, mtShift);

    GP p2; p2.A = Q; p2.B = Kb; p2.K = HD_; p2.lda = HD_; p2.ldb = HD_;
    p2.sA = (long)S_*HD_; p2.sB = (long)S_*HD_;
    p2.o0 = Sb; p2.bias = nullptr;
    gemm_bt<1><<<dim3(S_/128, S_/128, zc), dim3(256), 0, stream>>>(p2);

    softmax_rows<<<dim3(zc*S_/4), dim3(256), 0, stream>>>(Sb, Pb, mask + (long)c*bc*S_);

    GP p3; p3.A = Pb; p3.B = Vt; p3.K = S_; p3.lda = S_; p3.ldb = S_;
    p3.sA = (long)S_*S_; p3.sB = (long)S_*HD_;
    p3.o0 = H; p3.bias = nullptr;
    gemm_bt<2><<<dim3(HD_/128, S_/128, zc), dim3(256), 0, stream>>>(p3);

    // out projection: bias init + split-K(4) accumulate
    init_out_bias<<<dim3(rows_c*HD_/4/256), dim3(256), 0, stream>>>(
        (float4*)(out + row0*HD_), b_o, rows_c*HD_/4);
    GP p4; p4.A = H; p4.B = wob; p4.K = NHD_/4; p4.lda = NHD_; p4.ldb = NHD_;
    p4.sA = NHD_/4; p4.sB = NHD_/4;   // z indexes the K-chunk
    p4.o0 = out + row0*HD_; p4.bias = nullptr;
    gemm_bt<3><<<dim3(HD_/128, rows_c/128, 4), dim3(256), 0, stream>>>(p4);
  }
}

// Round 6
// 617.167 us; speedup vs baseline: 1.3161x; 1.1710x over previous
//
#include <hip/hip_runtime.h>
#include <hip/hip_bf16.h>
#include <stdint.h>

#define AS1 __attribute__((address_space(1)))
#define AS3 __attribute__((address_space(3)))

typedef __attribute__((ext_vector_type(8))) __bf16 bf16x8;
typedef __attribute__((ext_vector_type(4))) float f32x4;
typedef unsigned short u16;
typedef __attribute__((ext_vector_type(8))) unsigned short u16x8;

// ---- problem sizes (fixed for this module) ----
#define B_    8
#define S_    512
#define NH_   12
#define HD_   768
#define NHD_  (NH_*HD_)     // 9216
#define D3_   (3*NHD_)      // 27648
#define QK_SCALE 0.03608439182435161f   // 1/sqrt(768)

__device__ __forceinline__ u16 f2bf(float x) {
  union { float f; unsigned u; } a; a.f = x;
  unsigned r = a.u + 0x7fffu + ((a.u >> 16) & 1u);   // RNE
  return (u16)(r >> 16);
}
__device__ __forceinline__ float bf2f(u16 x) {
  union { unsigned u; float f; } a; a.u = ((unsigned)x) << 16; return a.f;
}

__device__ __forceinline__ void gload16(const void* g, void* l) {
  // async global->LDS; LDS dest = wave-uniform base + lane*16, global src per-lane
  __builtin_amdgcn_global_load_lds((const AS1 void*)g, (AS3 void*)l, 16, 0, 0);
}

// ============================================================================
// 128x128 GEMM, 256 threads (2x2 waves), BK=64, single-buffer 32KB LDS,
// ~5 blocks/CU resident (VGPR ~88, LDS 32KB) -> cross-block TLP hides
// prologue/epilogue/barriers (short-K regime, K=512..2304).
// T2 XOR swizzle on [128 rows][64 col] bf16 tiles (128B rows):
//   logical col16 c of row r stored at phys c ^ (r&7).
//   staging: gload i covers rows wave*8+(lane>>3) (+i*32), slot lane&7
//            -> global source col = ((lane&7) ^ (lane>>3)) * 8 elements.
//   read: row = base + (lane&15) -> row&7 = lane&7;
//         logical c16 = kk*4 + (lane>>4) -> phys = (c16 ^ (lane&7)) << 4.
//   Uniform 8 lanes per 16B-slot per wave-read -> ~0 bank conflicts (G4).
// MODE 0: QKV proj -> scatter Q,K (z,s,h) bf16 and Vt (z,h,s) bf16, +bias
// MODE 1: scores   -> S bf16 (z,row,col), * QK_SCALE
// MODE 2: AV       -> H bf16 at (b*512+row)*9216 + n*768 + col
// MODE 3: out-proj split-K partial -> fp32 part[z][row][col] (no bias)
// ============================================================================
struct GP {
  const u16* A;   // M x K row-major, lda
  const u16* B;   // N x K row-major, ldb  (C = A * B^T)
  int K, lda, ldb;
  long sA, sB;    // per-blockIdx.z element strides
  void* o0; void* o1; void* o2;
  const float* bias;
};

template<int MODE>
__global__ __launch_bounds__(256)
void gemm_bt(GP p) {
  __shared__ __align__(16) char smem[32768];   // A tile 16KB | B tile 16KB
  const int tid  = threadIdx.x;
  const int wave = tid >> 6, lane = tid & 63;
  const int wr = wave >> 1, wc = wave & 1;     // 2x2 waves, 64x64 each
  const int bm0 = blockIdx.y * 128;
  const int bn0 = blockIdx.x * 128;
  const int z   = blockIdx.z;

  const u16* A  = p.A + (long)z * p.sA;
  const u16* Bm = p.B + (long)z * p.sB;

  f32x4 acc[4][4];
  const f32x4 zero4 = {0.f, 0.f, 0.f, 0.f};
#pragma unroll
  for (int i = 0; i < 4; ++i)
#pragma unroll
    for (int j = 0; j < 4; ++j) acc[i][j] = zero4;

  // staging with pre-swizzled source column (see header comment)
  const int scolsw = ((lane & 7) ^ (lane >> 3)) * 8;   // elements
  const u16* gA = A  + (size_t)(bm0 + wave*8 + (lane>>3)) * p.lda + scolsw;
  const u16* gB = Bm + (size_t)(bn0 + wave*8 + (lane>>3)) * p.ldb + scolsw;
  char* ldsA = smem;
  char* ldsB = smem + 16384;
  char* stA  = ldsA + wave*1024;
  char* stB  = ldsB + wave*1024;

  // fragment read bases (row part) + per-kk swizzled column offsets
  const int aRow = (wr*64 + (lane&15)) * 128;
  const int bRow = (wc*64 + (lane&15)) * 128;
  const int csw  = lane & 7;
  const int cOff0 = (((lane>>4)    ) ^ csw) << 4;   // kk=0
  const int cOff1 = ((4 + (lane>>4)) ^ csw) << 4;   // kk=1

  for (int k0 = 0; k0 < p.K; k0 += 64) {
#pragma unroll
    for (int i = 0; i < 4; ++i) {
      gload16(gA + (size_t)i*32*p.lda, stA + i*4096);
      gload16(gB + (size_t)i*32*p.ldb, stB + i*4096);
    }
    gA += 64; gB += 64;
    __syncthreads();
#pragma unroll
    for (int kk = 0; kk < 2; ++kk) {
      const int cOff = kk ? cOff1 : cOff0;
      bf16x8 av[4], bv[4];
#pragma unroll
      for (int i = 0; i < 4; ++i)
        av[i] = *(const bf16x8*)(ldsA + aRow + i*2048 + cOff);
#pragma unroll
      for (int j = 0; j < 4; ++j)
        bv[j] = *(const bf16x8*)(ldsB + bRow + j*2048 + cOff);
#pragma unroll
      for (int i = 0; i < 4; ++i)
#pragma unroll
        for (int j = 0; j < 4; ++j)
          acc[i][j] = __builtin_amdgcn_mfma_f32_16x16x32_bf16(av[i], bv[j], acc[i][j], 0, 0, 0);
    }
    __syncthreads();
  }

  // epilogue: C/D layout col = lane&15, row = (lane>>4)*4 + reg  [m89]
  const int r0 = bm0 + wr*64 + ((lane>>4) << 2);
  const int c0 = bn0 + wc*64 + (lane&15);
#pragma unroll
  for (int i = 0; i < 4; ++i) {
#pragma unroll
    for (int j = 0; j < 4; ++j) {
      const int col = c0 + j*16;
#pragma unroll
      for (int r = 0; r < 4; ++r) {
        const int row = r0 + i*16 + r;
        const float v = acc[i][j][r];
        if constexpr (MODE == 0) {
          const float vb = v + p.bias[col];
          const int which = col / NHD_;
          const int rem = col - which*NHD_;
          const int n = rem / HD_;
          const int h = rem - n*HD_;
          const int bb = row >> 9, s = row & 511;     // chunk-local batch
          const long zz = (long)(bb*NH_ + n);
          if (which == 0)      ((u16*)p.o0)[zz*(long)(S_*HD_) + (long)s*HD_ + h] = f2bf(vb);
          else if (which == 1) ((u16*)p.o1)[zz*(long)(S_*HD_) + (long)s*HD_ + h] = f2bf(vb);
          else                 ((u16*)p.o2)[zz*(long)(S_*HD_) + (long)h*S_  + s] = f2bf(vb);
        } else if constexpr (MODE == 1) {
          ((u16*)p.o0)[(long)z*S_*S_ + (long)row*S_ + col] = f2bf(v * QK_SCALE);
        } else if constexpr (MODE == 2) {
          const int bb = z / NH_, n = z - bb*NH_;
          ((u16*)p.o0)[(long)(bb*S_ + row)*NHD_ + n*HD_ + col] = f2bf(v);
        } else {
          // split-K partial: part[z][row][col], rows_c = gridDim.y*128
          ((float*)p.o0)[((long)z * gridDim.y * 128 + row) * HD_ + col] = v;
        }
      }
    }
  }
}

// one wave per row (512 cols, bf16 in/out): +mask, softmax
__global__ __launch_bounds__(256)
void softmax_rows(const u16* __restrict__ S, u16* __restrict__ P,
                  const float* __restrict__ maskc) {
  const int wave = threadIdx.x >> 6, lane = threadIdx.x & 63;
  const int rid = blockIdx.x * 4 + wave;
  const int z = rid >> 9;
  const int b = z / NH_;
  const u16x8 sv = *(const u16x8*)(S + (size_t)rid * S_ + lane*8);
  const float* mrow = maskc + (size_t)b * S_;
  float vals[8];
  float m = -3.4e38f;
#pragma unroll
  for (int j = 0; j < 8; ++j) {
    vals[j] = bf2f(sv[j]) + mrow[lane*8 + j];
    m = fmaxf(m, vals[j]);
  }
#pragma unroll
  for (int o = 32; o > 0; o >>= 1) m = fmaxf(m, __shfl_xor(m, o));
  float sum = 0.f;
#pragma unroll
  for (int j = 0; j < 8; ++j) { vals[j] = __expf(vals[j] - m); sum += vals[j]; }
#pragma unroll
  for (int o = 32; o > 0; o >>= 1) sum += __shfl_xor(sum, o);
  const float inv = 1.0f / sum;
  u16x8 pv;
#pragma unroll
  for (int j = 0; j < 8; ++j) pv[j] = f2bf(vals[j] * inv);
  *(u16x8*)(P + (size_t)rid * S_ + lane*8) = pv;
}

__global__ __launch_bounds__(256)
void cvt_bf16(const float4* __restrict__ in, ushort4* __restrict__ out, int n4) {
  const int i = blockIdx.x * 256 + threadIdx.x;
  if (i >= n4) return;
  const float4 v = in[i];
  ushort4 o;
  o.x = f2bf(v.x); o.y = f2bf(v.y); o.z = f2bf(v.z); o.w = f2bf(v.w);
  out[i] = o;
}

// out = sum of 4 fp32 partials + bias; n4 = rows_c*768/4 (float4 units)
__global__ __launch_bounds__(256)
void combine_out(const float4* __restrict__ part, const float* __restrict__ b,
                 float4* __restrict__ out, int n4) {
  const int i = blockIdx.x * 256 + threadIdx.x;
  if (i >= n4) return;
  const float4 a0 = part[i];
  const float4 a1 = part[i + (size_t)n4];
  const float4 a2 = part[i + (size_t)2*n4];
  const float4 a3 = part[i + (size_t)3*n4];
  const int c = (i * 4) % HD_;
  float4 o;
  o.x = a0.x + a1.x + a2.x + a3.x + b[c];
  o.y = a0.y + a1.y + a2.y + a3.y + b[c+1];
  o.z = a0.z + a1.z + a2.z + a3.z + b[c+2];
  o.w = a0.w + a1.w + a2.w + a3.w + b[c+3];
  out[i] = o;
}

extern "C" void kernel_launch(void* const* d_in, const int* in_sizes, int n_in,
                              void* d_out, int out_size, void* d_ws, size_t ws_size,
                              hipStream_t stream) {
  const float* x     = (const float*)d_in[0];
  const float* mask  = (const float*)d_in[1];
  const float* w_qkv = (const float*)d_in[2];
  const float* b_qkv = (const float*)d_in[3];
  const float* w_o   = (const float*)d_in[4];
  const float* b_o   = (const float*)d_in[5];
  float* out = (float*)d_out;

  // adaptive batch-chunked workspace (layout proven rounds 2-5)
  // fixed: wqb 42,467,328 | wob 14,155,776
  // per-bc: xb bc*786,432 | Q,K,Vt bc*9,437,184 each | Sb bc*6,291,456
  // aliases: Pb=Kb (dead after scores), H=Q (dead after scores),
  //          out-proj partials = Sb (dead after softmax; 4*rows_c*768*4B == Sb size)
  int bc = 0;
  for (int c = 8; c >= 1; c >>= 1)
    if (56623104UL + (unsigned long)c*35389440UL <= ws_size) { bc = c; break; }
  if (bc == 0) return;

  char* ws = (char*)d_ws;
  u16* wqb = (u16*)(ws);
  u16* wob = (u16*)(ws + 42467328L);
  u16* xb  = (u16*)(ws + 56623104L);
  long off = 56623104L + (long)bc*786432L;
  u16* Q   = (u16*)(ws + off);  off += (long)bc*9437184L;
  u16* Kb  = (u16*)(ws + off);  off += (long)bc*9437184L;
  u16* Vt  = (u16*)(ws + off);  off += (long)bc*9437184L;
  u16* Sb  = (u16*)(ws + off);
  u16* Pb  = Kb;                 // alias
  u16* H   = Q;                  // alias
  float* Part = (float*)Sb;      // alias (4 x rows_c x 768 fp32 = Sb bytes)

  cvt_bf16<<<dim3(D3_*HD_/4/256), dim3(256), 0, stream>>>((const float4*)w_qkv, (ushort4*)wqb, D3_*HD_/4);
  cvt_bf16<<<dim3(HD_*NHD_/4/256), dim3(256), 0, stream>>>((const float4*)w_o, (ushort4*)wob, HD_*NHD_/4);

  const int nchunks = B_ / bc;
  const int rows_c = bc * S_;
  const int zc = bc * NH_;

  for (int c = 0; c < nchunks; ++c) {
    const long row0 = (long)c * rows_c;

    cvt_bf16<<<dim3(rows_c*HD_/4/256), dim3(256), 0, stream>>>(
        (const float4*)(x + row0*HD_), (ushort4*)xb, rows_c*HD_/4);

    GP p1; p1.A = xb; p1.B = wqb; p1.K = HD_; p1.lda = HD_; p1.ldb = HD_;
    p1.sA = 0; p1.sB = 0; p1.o0 = Q; p1.o1 = Kb; p1.o2 = Vt; p1.bias = b_qkv;
    gemm_bt<0><<<dim3(D3_/128, rows_c/128, 1), dim3(256), 0, stream>>>(p1);

    GP p2; p2.A = Q; p2.B = Kb; p2.K = HD_; p2.lda = HD_; p2.ldb = HD_;
    p2.sA = (long)S_*HD_; p2.sB = (long)S_*HD_;
    p2.o0 = Sb; p2.o1 = nullptr; p2.o2 = nullptr; p2.bias = nullptr;
    gemm_bt<1><<<dim3(S_/128, S_/128, zc), dim3(256), 0, stream>>>(p2);

    softmax_rows<<<dim3(zc*S_/4), dim3(256), 0, stream>>>(Sb, Pb, mask + (long)c*bc*S_);

    GP p3; p3.A = Pb; p3.B = Vt; p3.K = S_; p3.lda = S_; p3.ldb = S_;
    p3.sA = (long)S_*S_; p3.sB = (long)S_*HD_;
    p3.o0 = H; p3.o1 = nullptr; p3.o2 = nullptr; p3.bias = nullptr;
    gemm_bt<2><<<dim3(HD_/128, S_/128, zc), dim3(256), 0, stream>>>(p3);

    // out projection: split-K(4) partials into Sb (dead), then combine + bias
    GP p4; p4.A = H; p4.B = wob; p4.K = NHD_/4; p4.lda = NHD_; p4.ldb = NHD_;
    p4.sA = NHD_/4; p4.sB = NHD_/4;   // z indexes the K-chunk
    p4.o0 = Part; p4.o1 = nullptr; p4.o2 = nullptr; p4.bias = nullptr;
    gemm_bt<3><<<dim3(HD_/128, rows_c/128, 4), dim3(256), 0, stream>>>(p4);

    combine_out<<<dim3(rows_c*HD_/4/256), dim3(256), 0, stream>>>(
        (const float4*)Part, b_o, (float4*)(out + row0*HD_), rows_c*HD_/4);
  }
}